// Round 5
// baseline (488.130 us; speedup 1.0000x reference)
//
#include <hip/hip_runtime.h>

#define NMAT 2048
#define KATTR 64
#define CAP 128
#define NITER 10
#define SENT 2048  // sentinel: extra zeroed row of M; zeroed LDS col 2048

typedef unsigned short ushort4v __attribute__((ext_vector_type(4)));

__device__ __forceinline__ unsigned short f2bf(float f) {
  unsigned u = __float_as_uint(f);
  return (unsigned short)((u + 0x7fff + ((u >> 16) & 1)) >> 16);
}
__device__ __forceinline__ float bf2f(unsigned short b) {
  return __uint_as_float((unsigned)b << 16);
}
__device__ __forceinline__ float bflo(unsigned v) {
  return __uint_as_float(v << 16);
}
__device__ __forceinline__ float bfhi(unsigned v) {
  return __uint_as_float(v & 0xffff0000u);
}

// --------------------------------------------------------------------------
// Build padded adjacency (ELL); sentinel-fill to CAP (no scalar tails).
// idxT4 (Phase B): 4 edges/group at idxT4[g*NMAT*4 + r*4 + (p&3)].
// --------------------------------------------------------------------------
__global__ __launch_bounds__(256) void k_build(
    const float* __restrict__ A, unsigned short* __restrict__ idx,
    unsigned short* __restrict__ idxT4, int* __restrict__ cnt) {
  __shared__ int lcnt;
  int r = blockIdx.x;
  if (threadIdx.x == 0) lcnt = 0;
  __syncthreads();
  const float* row = A + (size_t)r * NMAT;
  for (int c = threadIdx.x; c < NMAT; c += 256) {
    if (row[c] != 0.0f) {
      int p = atomicAdd(&lcnt, 1);
      if (p < CAP) {
        idx[r * CAP + p] = (unsigned short)c;
        if (idxT4)
          idxT4[(size_t)(p >> 2) * (NMAT * 4) + r * 4 + (p & 3)] =
              (unsigned short)c;
      }
    }
  }
  __syncthreads();
  int n = lcnt < CAP ? lcnt : CAP;
  for (int p = n + threadIdx.x; p < CAP; p += 256) {
    idx[r * CAP + p] = (unsigned short)SENT;
    if (idxT4)
      idxT4[(size_t)(p >> 2) * (NMAT * 4) + r * 4 + (p & 3)] =
          (unsigned short)SENT;
  }
  if (threadIdx.x == 0) cnt[r] = n;
}

__global__ __launch_bounds__(256) void k_norm(const float* __restrict__ Nin,
                                              float* __restrict__ Nout) {
  int row = blockIdx.x * 4 + (threadIdx.x >> 6);
  int lane = threadIdx.x & 63;
  float v = Nin[(size_t)row * KATTR + lane];
  float ss = v * v;
#pragma unroll
  for (int o = 32; o > 0; o >>= 1) ss += __shfl_xor(ss, o);
  float nrm = sqrtf(ss);
  Nout[(size_t)row * KATTR + lane] = (nrm > 0.f) ? v / nrm : 0.f;
}

__global__ void k_gatherN(const unsigned short* __restrict__ idx,
                          const int* __restrict__ cnt,
                          const float* __restrict__ Nn,
                          float* __restrict__ C) {
  int i = blockIdx.x;
  int lane = threadIdx.x;  // blockDim = 64
  int nn = cnt[i];
  const unsigned short* ip = idx + i * CAP;
  float acc = 0.f;
  for (int t = 0; t < nn; ++t) {
    int k = ip[t];
    acc += Nn[(size_t)k * KATTR + lane];
  }
  C[(size_t)i * KATTR + lane] = acc;
}

__global__ __launch_bounds__(256) void k_transpose(const float* __restrict__ H,
                                                   float* __restrict__ Ht) {
  __shared__ float tile[64][65];
  int j0 = blockIdx.x * 64;
  int i0 = blockIdx.y * 64;
  int c = threadIdx.x & 63;
  int r0 = threadIdx.x >> 6;
  for (int r = r0; r < 64; r += 4)
    tile[r][c] = H[(size_t)(j0 + r) * NMAT + i0 + c];
  __syncthreads();
  for (int r = r0; r < 64; r += 4)
    Ht[(size_t)(i0 + r) * NMAT + j0 + c] = tile[c][r];
}

// Zero the sentinel row (row 2048) of the gather buffers, once.
__global__ __launch_bounds__(1024) void k_zrow(unsigned short* __restrict__ Mb0,
                                               unsigned short* __restrict__ Mb1,
                                               float* __restrict__ Mf) {
  size_t Z = (size_t)NMAT * NMAT;
  for (int o = threadIdx.x; o < NMAT; o += 1024) {
    Mb0[Z + o] = 0;
    Mb1[Z + o] = 0;
    Mf[Z + o] = 0.f;
  }
}

// --------------------------------------------------------------------------
// q = Nm>0&dm>0 ? Nm*rsqrt(Nm*dm) : 0.
// Outputs: M0gather = bf16(q*Ht), q (fp32, last iter),
// QM = pack(bf16(alpha*q^2) | bf16((1-a)*q*Ht) << 16).
// --------------------------------------------------------------------------
__global__ __launch_bounds__(256) void k_q(
    const float* __restrict__ N1n, const float* __restrict__ C1,
    const float* __restrict__ N2n, const float* __restrict__ C2,
    const float* __restrict__ Ht, float* __restrict__ q,
    unsigned* __restrict__ QM, unsigned short* __restrict__ M) {
  __shared__ float sA[64][68];
  __shared__ float sB[64][68];
  int i0 = blockIdx.y * 64, j0 = blockIdx.x * 64;
  int c = threadIdx.x & 63, r0 = threadIdx.x >> 6;
  int tx = threadIdx.x & 15, ty = threadIdx.x >> 4;
  const float alpha = 0.82f;

  float nmv[4][4] = {};
  float dmv[4][4] = {};

  for (int r = r0; r < 64; r += 4) {
    sA[c][r] = N1n[(size_t)(i0 + r) * KATTR + c];
    sB[c][r] = N2n[(size_t)(j0 + r) * KATTR + c];
  }
  __syncthreads();
#pragma unroll 4
  for (int k = 0; k < 64; ++k) {
    float4 a = *(const float4*)&sA[k][ty * 4];
    float4 b = *(const float4*)&sB[k][tx * 4];
    float av[4] = {a.x, a.y, a.z, a.w};
    float bv[4] = {b.x, b.y, b.z, b.w};
#pragma unroll
    for (int ii = 0; ii < 4; ++ii)
#pragma unroll
      for (int jj = 0; jj < 4; ++jj)
        nmv[ii][jj] = fmaf(av[ii], bv[jj], nmv[ii][jj]);
  }
  __syncthreads();
  for (int r = r0; r < 64; r += 4) {
    sA[c][r] = C1[(size_t)(i0 + r) * KATTR + c];
    sB[c][r] = C2[(size_t)(j0 + r) * KATTR + c];
  }
  __syncthreads();
#pragma unroll 4
  for (int k = 0; k < 64; ++k) {
    float4 a = *(const float4*)&sA[k][ty * 4];
    float4 b = *(const float4*)&sB[k][tx * 4];
    float av[4] = {a.x, a.y, a.z, a.w};
    float bv[4] = {b.x, b.y, b.z, b.w};
#pragma unroll
    for (int ii = 0; ii < 4; ++ii)
#pragma unroll
      for (int jj = 0; jj < 4; ++jj)
        dmv[ii][jj] = fmaf(av[ii], bv[jj], dmv[ii][jj]);
  }

#pragma unroll
  for (int ii = 0; ii < 4; ++ii) {
    int i = i0 + ty * 4 + ii;
    size_t base = (size_t)i * NMAT + j0 + tx * 4;
    float4 hv = *(const float4*)&Ht[base];
    float hvv[4] = {hv.x, hv.y, hv.z, hv.w};
    float qv[4];
    unsigned qmv[4];
    ushort4v mv;
#pragma unroll
    for (int jj = 0; jj < 4; ++jj) {
      float nmx = nmv[ii][jj];
      float D = nmx * dmv[ii][jj];
      float qq = (D > 0.f) ? nmx * rsqrtf(D) : 0.f;
      qv[jj] = qq;
      float m0 = qq * hvv[jj];
      mv[jj] = f2bf(m0);
      qmv[jj] = (unsigned)f2bf(alpha * qq * qq) |
                ((unsigned)f2bf((1.0f - alpha) * m0) << 16);
    }
    *(float4*)&q[base] = make_float4(qv[0], qv[1], qv[2], qv[3]);
    *(uint4*)&QM[base] = make_uint4(qmv[0], qmv[1], qmv[2], qmv[3]);
    *(ushort4v*)&M[base] = mv;
  }
}

// ---- Phase A gather macros (flat, no lambdas/arrays) ----
// bf16: per edge one uint2 = 4 cols; A0..A3 accumulate cols c0..c0+3.
#define A8U(pk, A0, A1, A2, A3)                                         \
  {                                                                     \
    uint2 w0 = *(const uint2*)(Bb + (size_t)((pk).x & 0xffff) * NMAT);  \
    uint2 w1 = *(const uint2*)(Bb + (size_t)((pk).x >> 16) * NMAT);     \
    uint2 w2 = *(const uint2*)(Bb + (size_t)((pk).y & 0xffff) * NMAT);  \
    uint2 w3 = *(const uint2*)(Bb + (size_t)((pk).y >> 16) * NMAT);     \
    uint2 w4 = *(const uint2*)(Bb + (size_t)((pk).z & 0xffff) * NMAT);  \
    uint2 w5 = *(const uint2*)(Bb + (size_t)((pk).z >> 16) * NMAT);     \
    uint2 w6 = *(const uint2*)(Bb + (size_t)((pk).w & 0xffff) * NMAT);  \
    uint2 w7 = *(const uint2*)(Bb + (size_t)((pk).w >> 16) * NMAT);     \
    A0 += ((bflo(w0.x) + bflo(w1.x)) + (bflo(w2.x) + bflo(w3.x))) +     \
          ((bflo(w4.x) + bflo(w5.x)) + (bflo(w6.x) + bflo(w7.x)));      \
    A1 += ((bfhi(w0.x) + bfhi(w1.x)) + (bfhi(w2.x) + bfhi(w3.x))) +     \
          ((bfhi(w4.x) + bfhi(w5.x)) + (bfhi(w6.x) + bfhi(w7.x)));      \
    A2 += ((bflo(w0.y) + bflo(w1.y)) + (bflo(w2.y) + bflo(w3.y))) +     \
          ((bflo(w4.y) + bflo(w5.y)) + (bflo(w6.y) + bflo(w7.y)));      \
    A3 += ((bfhi(w0.y) + bfhi(w1.y)) + (bfhi(w2.y) + bfhi(w3.y))) +     \
          ((bfhi(w4.y) + bfhi(w5.y)) + (bfhi(w6.y) + bfhi(w7.y)));      \
  }

#define A8F(pk, A0, A1, A2, A3)                                          \
  {                                                                      \
    float4 w0 = *(const float4*)(Bf + (size_t)((pk).x & 0xffff) * NMAT); \
    float4 w1 = *(const float4*)(Bf + (size_t)((pk).x >> 16) * NMAT);    \
    float4 w2 = *(const float4*)(Bf + (size_t)((pk).y & 0xffff) * NMAT); \
    float4 w3 = *(const float4*)(Bf + (size_t)((pk).y >> 16) * NMAT);    \
    float4 w4 = *(const float4*)(Bf + (size_t)((pk).z & 0xffff) * NMAT); \
    float4 w5 = *(const float4*)(Bf + (size_t)((pk).z >> 16) * NMAT);    \
    float4 w6 = *(const float4*)(Bf + (size_t)((pk).w & 0xffff) * NMAT); \
    float4 w7 = *(const float4*)(Bf + (size_t)((pk).w >> 16) * NMAT);    \
    A0 += ((w0.x + w1.x) + (w2.x + w3.x)) + ((w4.x + w5.x) + (w6.x + w7.x)); \
    A1 += ((w0.y + w1.y) + (w2.y + w3.y)) + ((w4.y + w5.y) + (w6.y + w7.y)); \
    A2 += ((w0.z + w1.z) + (w2.z + w3.z)) + ((w4.z + w5.z) + (w6.z + w7.z)); \
    A3 += ((w0.w + w1.w) + (w2.w + w3.w)) + ((w4.w + w5.w) + (w6.w + w7.w)); \
  }

#define GROWU(A0, A1, A2, A3, ROW)                 \
  {                                                \
    int nn = cnt1[ROW];                            \
    const unsigned short* ip = idx1 + (ROW) * CAP; \
    uint4 pA = *(const uint4*)ip;                  \
    uint4 pB = *(const uint4*)(ip + 8);            \
    A8U(pA, A0, A1, A2, A3);                       \
    A8U(pB, A0, A1, A2, A3);                       \
    for (int t = 16; t < nn; t += 8) {             \
      uint4 pk = *(const uint4*)(ip + t);          \
      A8U(pk, A0, A1, A2, A3);                     \
    }                                              \
  }

#define GROWF(A0, A1, A2, A3, ROW)                 \
  {                                                \
    int nn = cnt1[ROW];                            \
    const unsigned short* ip = idx1 + (ROW) * CAP; \
    uint4 pA = *(const uint4*)ip;                  \
    uint4 pB = *(const uint4*)(ip + 8);            \
    A8F(pA, A0, A1, A2, A3);                       \
    A8F(pB, A0, A1, A2, A3);                       \
    for (int t = 16; t < nn; t += 8) {             \
      uint4 pk = *(const uint4*)(ip + t);          \
      A8F(pk, A0, A1, A2, A3);                     \
    }                                              \
  }

// ---- Phase B gather macros ----
// bf16: one ds_read_b64 per edge; word0 = pk(r0,r1), word1 = pk(r2,r3).
#define B8U(ga, gb)                                          \
  {                                                          \
    uint2 wa = *(const uint2*)&ldsW[2 * ((ga).x & 0xffff)];  \
    uint2 wb = *(const uint2*)&ldsW[2 * ((ga).x >> 16)];     \
    uint2 wc = *(const uint2*)&ldsW[2 * ((ga).y & 0xffff)];  \
    uint2 wd = *(const uint2*)&ldsW[2 * ((ga).y >> 16)];     \
    uint2 we = *(const uint2*)&ldsW[2 * ((gb).x & 0xffff)];  \
    uint2 wf = *(const uint2*)&ldsW[2 * ((gb).x >> 16)];     \
    uint2 wg = *(const uint2*)&ldsW[2 * ((gb).y & 0xffff)];  \
    uint2 wh = *(const uint2*)&ldsW[2 * ((gb).y >> 16)];     \
    s0 += ((bflo(wa.x) + bflo(wb.x)) + (bflo(wc.x) + bflo(wd.x))) + \
          ((bflo(we.x) + bflo(wf.x)) + (bflo(wg.x) + bflo(wh.x))); \
    s1 += ((bfhi(wa.x) + bfhi(wb.x)) + (bfhi(wc.x) + bfhi(wd.x))) + \
          ((bfhi(we.x) + bfhi(wf.x)) + (bfhi(wg.x) + bfhi(wh.x))); \
    s2 += ((bflo(wa.y) + bflo(wb.y)) + (bflo(wc.y) + bflo(wd.y))) + \
          ((bflo(we.y) + bflo(wf.y)) + (bflo(wg.y) + bflo(wh.y))); \
    s3 += ((bfhi(wa.y) + bfhi(wb.y)) + (bfhi(wc.y) + bfhi(wd.y))) + \
          ((bfhi(we.y) + bfhi(wf.y)) + (bfhi(wg.y) + bfhi(wh.y))); \
  }

#define B8F(ga, gb)                                            \
  {                                                            \
    float4 va = *(const float4*)&ldsW[4 * ((ga).x & 0xffff)];  \
    float4 vb = *(const float4*)&ldsW[4 * ((ga).x >> 16)];     \
    float4 vc = *(const float4*)&ldsW[4 * ((ga).y & 0xffff)];  \
    float4 vd = *(const float4*)&ldsW[4 * ((ga).y >> 16)];     \
    float4 ve = *(const float4*)&ldsW[4 * ((gb).x & 0xffff)];  \
    float4 vf = *(const float4*)&ldsW[4 * ((gb).x >> 16)];     \
    float4 vg = *(const float4*)&ldsW[4 * ((gb).y & 0xffff)];  \
    float4 vh = *(const float4*)&ldsW[4 * ((gb).y >> 16)];     \
    s0 += ((va.x + vb.x) + (vc.x + vd.x)) + ((ve.x + vf.x) + (vg.x + vh.x)); \
    s1 += ((va.y + vb.y) + (vc.y + vd.y)) + ((ve.y + vf.y) + (vg.y + vh.y)); \
    s2 += ((va.z + vb.z) + (vc.z + vd.z)) + ((ve.z + vf.z) + (vg.z + vh.z)); \
    s3 += ((va.w + vb.w) + (vc.w + vd.w)) + ((ve.w + vf.w) + (vg.w + vh.w)); \
  }

// --------------------------------------------------------------------------
// One full iteration, fused (v6b = v6 algorithm, hardened codegen).
// Grid 512 x 1024 (32 waves/CU).
//  - Phase A row-split: half-block gathers rows {0,1}, other half {2,3},
//    4 cols/thread via uint2 (8B/lane): VMEM wave-instrs halve vs v5.
//  - T1 packed bf16x4 per column: Phase B = one ds_read_b64 per edge for
//    all 4 rows (bf16 T1 proven numerically fine in v4, absmax 1.9e-9).
//  - fp32 float4 LDS path for the last (in32) iteration only.
// --------------------------------------------------------------------------
__global__ __launch_bounds__(1024, 8) void k_iter(
    const unsigned short* __restrict__ idx1, const int* __restrict__ cnt1,
    const unsigned short* __restrict__ idx2T4, const int* __restrict__ cnt2,
    const unsigned short* __restrict__ Min, const float* __restrict__ MinF,
    const unsigned* __restrict__ QM, const float* __restrict__ q,
    const float* __restrict__ Ht, unsigned short* __restrict__ Mout,
    float* __restrict__ MoutF, float* __restrict__ sout, int in32, int out32,
    int last) {
  // word-addressed LDS: bf16 view uses words [2c,2c+1]; fp32 view [4c..4c+3]
  __shared__ unsigned ldsW[(NMAT + 2) * 4];
  const int GS = NMAT * 4;  // idx2T4 group stride (ushorts)
  int i0 = blockIdx.x * 4;
  int tid = threadIdx.x;  // 0..1023

  if (tid == 0) {
    ldsW[2 * SENT] = 0u;
    ldsW[2 * SENT + 1] = 0u;
    ldsW[4 * SENT] = 0u;
    ldsW[4 * SENT + 1] = 0u;
    ldsW[4 * SENT + 2] = 0u;
    ldsW[4 * SENT + 3] = 0u;
  }

  // ---- Phase A: row gathers, row-split halves ----
  int half = tid >> 9;  // 0: rows i0,i0+1   1: rows i0+2,i0+3
  int lt = tid & 511;
  int c0 = lt * 4;  // this half-thread's 4 columns
  int ra = i0 + half * 2;
  float xA0 = 0.f, xA1 = 0.f, xA2 = 0.f, xA3 = 0.f;  // row ra
  float xB0 = 0.f, xB1 = 0.f, xB2 = 0.f, xB3 = 0.f;  // row ra+1
  if (in32) {
    const float* Bf = MinF + c0;
    GROWF(xA0, xA1, xA2, xA3, ra);
    GROWF(xB0, xB1, xB2, xB3, ra + 1);
    // store: col c words 4c+2*half,+1 = (row ra, row ra+1)
    *(float2*)&ldsW[4 * (c0 + 0) + 2 * half] = make_float2(xA0, xB0);
    *(float2*)&ldsW[4 * (c0 + 1) + 2 * half] = make_float2(xA1, xB1);
    *(float2*)&ldsW[4 * (c0 + 2) + 2 * half] = make_float2(xA2, xB2);
    *(float2*)&ldsW[4 * (c0 + 3) + 2 * half] = make_float2(xA3, xB3);
  } else {
    const unsigned short* Bb = Min + c0;
    GROWU(xA0, xA1, xA2, xA3, ra);
    GROWU(xB0, xB1, xB2, xB3, ra + 1);
    // store: col c word 2c+half = pack(bf16(row ra), bf16(row ra+1))
    ldsW[2 * (c0 + 0) + half] =
        (unsigned)f2bf(xA0) | ((unsigned)f2bf(xB0) << 16);
    ldsW[2 * (c0 + 1) + half] =
        (unsigned)f2bf(xA1) | ((unsigned)f2bf(xB1) << 16);
    ldsW[2 * (c0 + 2) + half] =
        (unsigned)f2bf(xA2) | ((unsigned)f2bf(xB2) << 16);
    ldsW[2 * (c0 + 3) + half] =
        (unsigned)f2bf(xA3) | ((unsigned)f2bf(xB3) << 16);
  }
  __syncthreads();

  // ---- Phase B: column gathers from LDS + epilogue ----
  const float alpha = 0.82f;
  const float oma = 1.0f - alpha;
#pragma unroll
  for (int jj = 0; jj < 2; ++jj) {
    int j = jj * 1024 + tid;
    int nn = cnt2[j];
    const unsigned short* bp = idx2T4 + j * 4;
    size_t off0 = (size_t)i0 * NMAT + j;
    // prefetch epilogue operands (hide under gather)
    unsigned wq0 = 0, wq1 = 0, wq2 = 0, wq3 = 0;
    if (!last) {
      wq0 = QM[off0];
      wq1 = QM[off0 + NMAT];
      wq2 = QM[off0 + 2 * NMAT];
      wq3 = QM[off0 + 3 * NMAT];
    }
    uint2 g0 = *(const uint2*)(bp);
    uint2 g1 = *(const uint2*)(bp + GS);
    uint2 g2 = *(const uint2*)(bp + 2 * GS);
    uint2 g3 = *(const uint2*)(bp + 3 * GS);
    float s0 = 0.f, s1 = 0.f, s2 = 0.f, s3 = 0.f;
    if (in32) {
      B8F(g0, g1);
      B8F(g2, g3);
      for (int t = 16; t < nn; t += 8) {
        uint2 ga = *(const uint2*)(bp + (size_t)(t >> 2) * GS);
        uint2 gb = *(const uint2*)(bp + (size_t)((t >> 2) + 1) * GS);
        B8F(ga, gb);
      }
    } else {
      B8U(g0, g1);
      B8U(g2, g3);
      for (int t = 16; t < nn; t += 8) {
        uint2 ga = *(const uint2*)(bp + (size_t)(t >> 2) * GS);
        uint2 gb = *(const uint2*)(bp + (size_t)((t >> 2) + 1) * GS);
        B8U(ga, gb);
      }
    }
    if (last) {
      sout[off0] = oma * Ht[off0] + alpha * q[off0] * s0;
      size_t o1 = off0 + NMAT;
      sout[o1] = oma * Ht[o1] + alpha * q[o1] * s1;
      size_t o2 = off0 + 2 * NMAT;
      sout[o2] = oma * Ht[o2] + alpha * q[o2] * s2;
      size_t o3 = off0 + 3 * NMAT;
      sout[o3] = oma * Ht[o3] + alpha * q[o3] * s3;
    } else if (out32) {
      MoutF[off0] = fmaf(bflo(wq0), s0, bfhi(wq0));
      MoutF[off0 + NMAT] = fmaf(bflo(wq1), s1, bfhi(wq1));
      MoutF[off0 + 2 * NMAT] = fmaf(bflo(wq2), s2, bfhi(wq2));
      MoutF[off0 + 3 * NMAT] = fmaf(bflo(wq3), s3, bfhi(wq3));
    } else {
      Mout[off0] = f2bf(fmaf(bflo(wq0), s0, bfhi(wq0)));
      Mout[off0 + NMAT] = f2bf(fmaf(bflo(wq1), s1, bfhi(wq1)));
      Mout[off0 + 2 * NMAT] = f2bf(fmaf(bflo(wq2), s2, bfhi(wq2)));
      Mout[off0 + 3 * NMAT] = f2bf(fmaf(bflo(wq3), s3, bfhi(wq3)));
    }
  }
}

extern "C" void kernel_launch(void* const* d_in, const int* in_sizes, int n_in,
                              void* d_out, int out_size, void* d_ws,
                              size_t ws_size, hipStream_t stream) {
  const float* A1 = (const float*)d_in[0];
  const float* A2 = (const float*)d_in[1];
  const float* N1 = (const float*)d_in[2];
  const float* N2 = (const float*)d_in[3];
  const float* H = (const float*)d_in[4];
  float* s_out = (float*)d_out;

  char* p = (char*)d_ws;
  auto take = [&](size_t bytes) {
    char* r = p;
    p += (bytes + 255) & ~(size_t)255;
    return r;
  };
  unsigned short* idx1 = (unsigned short*)take((size_t)NMAT * CAP * 2);
  unsigned short* idx2 = (unsigned short*)take((size_t)NMAT * CAP * 2);
  unsigned short* idx2T4 = (unsigned short*)take((size_t)CAP * NMAT * 2);
  int* cnt1 = (int*)take((size_t)NMAT * 4);
  int* cnt2 = (int*)take((size_t)NMAT * 4);
  float* N1n = (float*)take((size_t)NMAT * KATTR * 4);
  float* N2n = (float*)take((size_t)NMAT * KATTR * 4);
  float* C1 = (float*)take((size_t)NMAT * KATTR * 4);
  float* C2 = (float*)take((size_t)NMAT * KATTR * 4);
  float* Ht = (float*)take((size_t)NMAT * NMAT * 4);
  float* q = (float*)take((size_t)NMAT * NMAT * 4);
  unsigned* QM = (unsigned*)take((size_t)NMAT * NMAT * 4);
  unsigned short* Mb0 = (unsigned short*)take((size_t)(NMAT + 1) * NMAT * 2);
  unsigned short* Mb1 = (unsigned short*)take((size_t)(NMAT + 1) * NMAT * 2);
  float* Mf = (float*)take((size_t)(NMAT + 1) * NMAT * 4);
  if ((size_t)(p - (char*)d_ws) > ws_size) return;

  k_build<<<NMAT, 256, 0, stream>>>(A1, idx1, (unsigned short*)nullptr, cnt1);
  k_build<<<NMAT, 256, 0, stream>>>(A2, idx2, idx2T4, cnt2);
  k_norm<<<NMAT / 4, 256, 0, stream>>>(N1, N1n);
  k_norm<<<NMAT / 4, 256, 0, stream>>>(N2, N2n);
  k_gatherN<<<NMAT, 64, 0, stream>>>(idx1, cnt1, N1n, C1);
  k_gatherN<<<NMAT, 64, 0, stream>>>(idx2, cnt2, N2n, C2);
  k_transpose<<<dim3(32, 32), 256, 0, stream>>>(H, Ht);
  k_q<<<dim3(32, 32), 256, 0, stream>>>(N1n, C1, N2n, C2, Ht, q, QM, Mb0);
  k_zrow<<<1, 1024, 0, stream>>>(Mb0, Mb1, Mf);
  for (int it = 0; it < NITER; ++it) {
    const unsigned short* Min = (it & 1) ? Mb1 : Mb0;
    unsigned short* Mout = (it & 1) ? Mb0 : Mb1;
    int in32 = (it == NITER - 1) ? 1 : 0;
    int out32 = (it == NITER - 2) ? 1 : 0;
    int last = (it == NITER - 1) ? 1 : 0;
    k_iter<<<NMAT / 4, 1024, 0, stream>>>(idx1, cnt1, idx2T4, cnt2, Min, Mf,
                                          QM, q, Ht, Mout, Mf, s_out, in32,
                                          out32, last);
  }
}

// Round 6
// 406.173 us; speedup vs baseline: 1.2018x; 1.2018x over previous
//
#include <hip/hip_runtime.h>

#define NMAT 2048
#define KATTR 64
#define CAP 64
#define NITER 10
#define SENT_A 2048  // Phase A sentinel: extra zeroed row of M buffers
#define SENT_B 2057  // Phase B sentinel: swz(2057)=8232, outside real swz image

typedef unsigned short ushort4v __attribute__((ext_vector_type(4)));

__device__ __forceinline__ unsigned short f2bf(float f) {
  unsigned u = __float_as_uint(f);
  return (unsigned short)((u + 0x7fff + ((u >> 16) & 1)) >> 16);
}
__device__ __forceinline__ float bf2f(unsigned short b) {
  return __uint_as_float((unsigned)b << 16);
}
__device__ __forceinline__ float bflo(unsigned v) {
  return __uint_as_float(v << 16);
}
__device__ __forceinline__ float bfhi(unsigned v) {
  return __uint_as_float(v & 0xffff0000u);
}
// swizzled LDS dword index (proven v3/v5): real cols map to [0, 8219+3];
// SENT_B=2057 maps to 8232..8235 (zeroed, disjoint from all real cols).
__device__ __forceinline__ int swz(int c) { return 4 * c + (((c >> 3) & 7) << 2); }

// --------------------------------------------------------------------------
// Build padded adjacency (ELL); sentinel-fill unused slots up to CAP so the
// gather loops never need scalar tails.
// idxT4 (Phase B): 4 edges/group at idxT4[g*NMAT*4 + r*4 + (p&3)].
// --------------------------------------------------------------------------
__global__ __launch_bounds__(256) void k_build(
    const float* __restrict__ A, unsigned short* __restrict__ idx,
    unsigned short* __restrict__ idxT4, int* __restrict__ cnt) {
  __shared__ int lcnt;
  int r = blockIdx.x;
  if (threadIdx.x == 0) lcnt = 0;
  __syncthreads();
  const float* row = A + (size_t)r * NMAT;
  for (int c = threadIdx.x; c < NMAT; c += 256) {
    if (row[c] != 0.0f) {
      int p = atomicAdd(&lcnt, 1);
      if (p < CAP) {
        idx[r * CAP + p] = (unsigned short)c;
        if (idxT4)
          idxT4[(size_t)(p >> 2) * (NMAT * 4) + r * 4 + (p & 3)] =
              (unsigned short)c;
      }
    }
  }
  __syncthreads();
  int n = lcnt < CAP ? lcnt : CAP;
  for (int p = n + threadIdx.x; p < CAP; p += 256) {
    idx[r * CAP + p] = (unsigned short)SENT_A;
    if (idxT4)
      idxT4[(size_t)(p >> 2) * (NMAT * 4) + r * 4 + (p & 3)] =
          (unsigned short)SENT_B;
  }
  if (threadIdx.x == 0) cnt[r] = n;
}

__global__ __launch_bounds__(256) void k_norm(const float* __restrict__ Nin,
                                              float* __restrict__ Nout) {
  int row = blockIdx.x * 4 + (threadIdx.x >> 6);
  int lane = threadIdx.x & 63;
  float v = Nin[(size_t)row * KATTR + lane];
  float ss = v * v;
#pragma unroll
  for (int o = 32; o > 0; o >>= 1) ss += __shfl_xor(ss, o);
  float nrm = sqrtf(ss);
  Nout[(size_t)row * KATTR + lane] = (nrm > 0.f) ? v / nrm : 0.f;
}

__global__ void k_gatherN(const unsigned short* __restrict__ idx,
                          const int* __restrict__ cnt,
                          const float* __restrict__ Nn,
                          float* __restrict__ C) {
  int i = blockIdx.x;
  int lane = threadIdx.x;  // blockDim = 64
  int nn = cnt[i];
  const unsigned short* ip = idx + i * CAP;
  float acc = 0.f;
  for (int t = 0; t < nn; ++t) {
    int k = ip[t];
    acc += Nn[(size_t)k * KATTR + lane];
  }
  C[(size_t)i * KATTR + lane] = acc;
}

__global__ __launch_bounds__(256) void k_transpose(const float* __restrict__ H,
                                                   float* __restrict__ Ht) {
  __shared__ float tile[64][65];
  int j0 = blockIdx.x * 64;
  int i0 = blockIdx.y * 64;
  int c = threadIdx.x & 63;
  int r0 = threadIdx.x >> 6;
  for (int r = r0; r < 64; r += 4)
    tile[r][c] = H[(size_t)(j0 + r) * NMAT + i0 + c];
  __syncthreads();
  for (int r = r0; r < 64; r += 4)
    Ht[(size_t)(i0 + r) * NMAT + j0 + c] = tile[c][r];
}

// Zero the sentinel row (row 2048) of the gather buffers, once.
__global__ __launch_bounds__(1024) void k_zrow(unsigned short* __restrict__ Mb0,
                                               unsigned short* __restrict__ Mb1) {
  size_t Z = (size_t)NMAT * NMAT;
  for (int o = threadIdx.x; o < NMAT; o += 1024) {
    Mb0[Z + o] = 0;
    Mb1[Z + o] = 0;
  }
}

// --------------------------------------------------------------------------
// q = Nm>0&dm>0 ? Nm*rsqrt(Nm*dm) : 0.
// Outputs: M0gather = bf16(q*Ht),
// QM = pack(bf16(alpha*q^2)      | bf16((1-a)*q*Ht) << 16)  (iters 0..8)
// QL = pack(bf16(alpha*q)        | bf16((1-a)*Ht)   << 16)  (last iter:
//   s = (1-a)*Ht + alpha*q*S = bfhi(QL) + bflo(QL)*S)
// --------------------------------------------------------------------------
__global__ __launch_bounds__(256) void k_q(
    const float* __restrict__ N1n, const float* __restrict__ C1,
    const float* __restrict__ N2n, const float* __restrict__ C2,
    const float* __restrict__ Ht, unsigned* __restrict__ QM,
    unsigned* __restrict__ QL, unsigned short* __restrict__ M) {
  __shared__ float sA[64][68];
  __shared__ float sB[64][68];
  int i0 = blockIdx.y * 64, j0 = blockIdx.x * 64;
  int c = threadIdx.x & 63, r0 = threadIdx.x >> 6;
  int tx = threadIdx.x & 15, ty = threadIdx.x >> 4;
  const float alpha = 0.82f;

  float nmv[4][4] = {};
  float dmv[4][4] = {};

  for (int r = r0; r < 64; r += 4) {
    sA[c][r] = N1n[(size_t)(i0 + r) * KATTR + c];
    sB[c][r] = N2n[(size_t)(j0 + r) * KATTR + c];
  }
  __syncthreads();
#pragma unroll 4
  for (int k = 0; k < 64; ++k) {
    float4 a = *(const float4*)&sA[k][ty * 4];
    float4 b = *(const float4*)&sB[k][tx * 4];
    float av[4] = {a.x, a.y, a.z, a.w};
    float bv[4] = {b.x, b.y, b.z, b.w};
#pragma unroll
    for (int ii = 0; ii < 4; ++ii)
#pragma unroll
      for (int jj = 0; jj < 4; ++jj)
        nmv[ii][jj] = fmaf(av[ii], bv[jj], nmv[ii][jj]);
  }
  __syncthreads();
  for (int r = r0; r < 64; r += 4) {
    sA[c][r] = C1[(size_t)(i0 + r) * KATTR + c];
    sB[c][r] = C2[(size_t)(j0 + r) * KATTR + c];
  }
  __syncthreads();
#pragma unroll 4
  for (int k = 0; k < 64; ++k) {
    float4 a = *(const float4*)&sA[k][ty * 4];
    float4 b = *(const float4*)&sB[k][tx * 4];
    float av[4] = {a.x, a.y, a.z, a.w};
    float bv[4] = {b.x, b.y, b.z, b.w};
#pragma unroll
    for (int ii = 0; ii < 4; ++ii)
#pragma unroll
      for (int jj = 0; jj < 4; ++jj)
        dmv[ii][jj] = fmaf(av[ii], bv[jj], dmv[ii][jj]);
  }

#pragma unroll
  for (int ii = 0; ii < 4; ++ii) {
    int i = i0 + ty * 4 + ii;
    size_t base = (size_t)i * NMAT + j0 + tx * 4;
    float4 hv = *(const float4*)&Ht[base];
    float hvv[4] = {hv.x, hv.y, hv.z, hv.w};
    unsigned qmv[4], qlv[4];
    ushort4v mv;
#pragma unroll
    for (int jj = 0; jj < 4; ++jj) {
      float nmx = nmv[ii][jj];
      float D = nmx * dmv[ii][jj];
      float qq = (D > 0.f) ? nmx * rsqrtf(D) : 0.f;
      float m0 = qq * hvv[jj];
      mv[jj] = f2bf(m0);
      qmv[jj] = (unsigned)f2bf(alpha * qq * qq) |
                ((unsigned)f2bf((1.0f - alpha) * m0) << 16);
      qlv[jj] = (unsigned)f2bf(alpha * qq) |
                ((unsigned)f2bf((1.0f - alpha) * hvv[jj]) << 16);
    }
    *(uint4*)&QM[base] = make_uint4(qmv[0], qmv[1], qmv[2], qmv[3]);
    *(uint4*)&QL[base] = make_uint4(qlv[0], qlv[1], qlv[2], qlv[3]);
    *(ushort4v*)&M[base] = mv;
  }
}

// --------------------------------------------------------------------------
// One full iteration, fused (v7 = v5 structure, all-bf16, fp32 path deleted).
// Grid 512 x 1024 (16 waves/block, 2 blocks/CU = 32 waves/CU).
// Phase A: whole-row index preload + 4B/lane bf16-pair gathers (v5-proven).
// Phase B: one ds_read_b128 per edge from swizzled T1 + packed-word epilogue.
// QMx = QM for iters 0..8 (Mout = fmaf(bflo,S,bfhi) in bf16),
//       QL for the last (sout = bfhi + bflo*S in fp32).
// --------------------------------------------------------------------------
__global__ __launch_bounds__(1024, 8) void k_iter(
    const unsigned short* __restrict__ idx1, const int* __restrict__ cnt1,
    const unsigned short* __restrict__ idx2T4, const int* __restrict__ cnt2,
    const unsigned short* __restrict__ Min, const unsigned* __restrict__ QMx,
    unsigned short* __restrict__ Mout, float* __restrict__ sout, int last) {
  __shared__ float lds[4 * NMAT + 64];
  const int GS = NMAT * 4;  // idx2T4 group stride (ushorts)
  int i0 = blockIdx.x * 4;
  int tid = threadIdx.x;  // 0..1023
  int c0 = tid * 2;       // this thread's 2 columns

  if (tid == 0) *(float4*)&lds[swz(SENT_B)] = make_float4(0.f, 0.f, 0.f, 0.f);

  // ---- Phase A: row gathers ----
  float acc[4][2];
#pragma unroll
  for (int r = 0; r < 4; ++r) {
    int nn = cnt1[i0 + r];
    const unsigned short* ip = idx1 + (i0 + r) * CAP;
    // whole-row index preload (sentinel-padded, always valid)
    uint4 pA = *(const uint4*)(ip);
    uint4 pB = *(const uint4*)(ip + 8);
    uint4 pC = *(const uint4*)(ip + 16);
    uint4 pD = *(const uint4*)(ip + 24);
    float a0 = 0.f, a1 = 0.f;
    const unsigned short* Bb = Min + c0;
    auto g8 = [&](uint4 pk, unsigned* w) {
      w[0] = *(const unsigned*)(Bb + (size_t)(pk.x & 0xffff) * NMAT);
      w[1] = *(const unsigned*)(Bb + (size_t)(pk.x >> 16) * NMAT);
      w[2] = *(const unsigned*)(Bb + (size_t)(pk.y & 0xffff) * NMAT);
      w[3] = *(const unsigned*)(Bb + (size_t)(pk.y >> 16) * NMAT);
      w[4] = *(const unsigned*)(Bb + (size_t)(pk.z & 0xffff) * NMAT);
      w[5] = *(const unsigned*)(Bb + (size_t)(pk.z >> 16) * NMAT);
      w[6] = *(const unsigned*)(Bb + (size_t)(pk.w & 0xffff) * NMAT);
      w[7] = *(const unsigned*)(Bb + (size_t)(pk.w >> 16) * NMAT);
    };
    unsigned w[16];
    g8(pA, w);
    g8(pB, w + 8);
    bool more = nn > 16;
    unsigned w2[16];
    if (more) {
      g8(pC, w2);
      g8(pD, w2 + 8);
    }
#pragma unroll
    for (int e = 0; e < 16; ++e) {
      a0 += bflo(w[e]);
      a1 += bfhi(w[e]);
    }
    if (more) {
#pragma unroll
      for (int e = 0; e < 16; ++e) {
        a0 += bflo(w2[e]);
        a1 += bfhi(w2[e]);
      }
    }
    for (int t = 32; t < nn; t += 8) {
      uint4 pk = *(const uint4*)(ip + t);
      unsigned w3[8];
      g8(pk, w3);
#pragma unroll
      for (int e = 0; e < 8; ++e) {
        a0 += bflo(w3[e]);
        a1 += bfhi(w3[e]);
      }
    }
    acc[r][0] = a0;
    acc[r][1] = a1;
  }
  *(float4*)&lds[swz(c0)] =
      make_float4(acc[0][0], acc[1][0], acc[2][0], acc[3][0]);
  *(float4*)&lds[swz(c0 + 1)] =
      make_float4(acc[0][1], acc[1][1], acc[2][1], acc[3][1]);
  __syncthreads();

  // ---- Phase B: column gathers from LDS + epilogue ----
#pragma unroll
  for (int jj = 0; jj < 2; ++jj) {
    int j = jj * 1024 + tid;
    int nn = cnt2[j];
    const unsigned short* bp = idx2T4 + j * 4;
    size_t off0 = (size_t)i0 * NMAT + j;
    // prefetch epilogue operands (hide under gather)
    unsigned wq0 = QMx[off0];
    unsigned wq1 = QMx[off0 + NMAT];
    unsigned wq2 = QMx[off0 + 2 * NMAT];
    unsigned wq3 = QMx[off0 + 3 * NMAT];
    // first 16 edges unconditionally (sentinel slots are zeroed broadcast)
    uint2 g0 = *(const uint2*)(bp);
    uint2 g1 = *(const uint2*)(bp + GS);
    uint2 g2 = *(const uint2*)(bp + 2 * GS);
    uint2 g3 = *(const uint2*)(bp + 3 * GS);
    float s0 = 0.f, s1 = 0.f, s2 = 0.f, s3 = 0.f;
    float u0 = 0.f, u1 = 0.f, u2 = 0.f, u3 = 0.f;
    {
      float4 va = *(const float4*)&lds[swz(g0.x & 0xffff)];
      float4 vb = *(const float4*)&lds[swz(g0.x >> 16)];
      float4 vc = *(const float4*)&lds[swz(g0.y & 0xffff)];
      float4 vd = *(const float4*)&lds[swz(g0.y >> 16)];
      float4 ve = *(const float4*)&lds[swz(g1.x & 0xffff)];
      float4 vf = *(const float4*)&lds[swz(g1.x >> 16)];
      float4 vg = *(const float4*)&lds[swz(g1.y & 0xffff)];
      float4 vh = *(const float4*)&lds[swz(g1.y >> 16)];
      s0 += (va.x + vb.x) + (vc.x + vd.x);
      s1 += (va.y + vb.y) + (vc.y + vd.y);
      s2 += (va.z + vb.z) + (vc.z + vd.z);
      s3 += (va.w + vb.w) + (vc.w + vd.w);
      u0 += (ve.x + vf.x) + (vg.x + vh.x);
      u1 += (ve.y + vf.y) + (vg.y + vh.y);
      u2 += (ve.z + vf.z) + (vg.z + vh.z);
      u3 += (ve.w + vf.w) + (vg.w + vh.w);
    }
    {
      float4 va = *(const float4*)&lds[swz(g2.x & 0xffff)];
      float4 vb = *(const float4*)&lds[swz(g2.x >> 16)];
      float4 vc = *(const float4*)&lds[swz(g2.y & 0xffff)];
      float4 vd = *(const float4*)&lds[swz(g2.y >> 16)];
      float4 ve = *(const float4*)&lds[swz(g3.x & 0xffff)];
      float4 vf = *(const float4*)&lds[swz(g3.x >> 16)];
      float4 vg = *(const float4*)&lds[swz(g3.y & 0xffff)];
      float4 vh = *(const float4*)&lds[swz(g3.y >> 16)];
      s0 += (va.x + vb.x) + (vc.x + vd.x);
      s1 += (va.y + vb.y) + (vc.y + vd.y);
      s2 += (va.z + vb.z) + (vc.z + vd.z);
      s3 += (va.w + vb.w) + (vc.w + vd.w);
      u0 += (ve.x + vf.x) + (vg.x + vh.x);
      u1 += (ve.y + vf.y) + (vg.y + vh.y);
      u2 += (ve.z + vf.z) + (vg.z + vh.z);
      u3 += (ve.w + vf.w) + (vg.w + vh.w);
    }
    for (int t = 16; t < nn; t += 8) {
      uint2 ga = *(const uint2*)(bp + (size_t)(t >> 2) * GS);
      uint2 gb = *(const uint2*)(bp + (size_t)((t >> 2) + 1) * GS);
      float4 va = *(const float4*)&lds[swz(ga.x & 0xffff)];
      float4 vb = *(const float4*)&lds[swz(ga.x >> 16)];
      float4 vc = *(const float4*)&lds[swz(ga.y & 0xffff)];
      float4 vd = *(const float4*)&lds[swz(ga.y >> 16)];
      float4 ve = *(const float4*)&lds[swz(gb.x & 0xffff)];
      float4 vf = *(const float4*)&lds[swz(gb.x >> 16)];
      float4 vg = *(const float4*)&lds[swz(gb.y & 0xffff)];
      float4 vh = *(const float4*)&lds[swz(gb.y >> 16)];
      s0 += (va.x + vb.x) + (vc.x + vd.x);
      s1 += (va.y + vb.y) + (vc.y + vd.y);
      s2 += (va.z + vb.z) + (vc.z + vd.z);
      s3 += (va.w + vb.w) + (vc.w + vd.w);
      u0 += (ve.x + vf.x) + (vg.x + vh.x);
      u1 += (ve.y + vf.y) + (vg.y + vh.y);
      u2 += (ve.z + vf.z) + (vg.z + vh.z);
      u3 += (ve.w + vf.w) + (vg.w + vh.w);
    }
    float sa[4] = {s0 + u0, s1 + u1, s2 + u2, s3 + u3};
    if (last) {
      sout[off0] = fmaf(bflo(wq0), sa[0], bfhi(wq0));
      sout[off0 + NMAT] = fmaf(bflo(wq1), sa[1], bfhi(wq1));
      sout[off0 + 2 * NMAT] = fmaf(bflo(wq2), sa[2], bfhi(wq2));
      sout[off0 + 3 * NMAT] = fmaf(bflo(wq3), sa[3], bfhi(wq3));
    } else {
      Mout[off0] = f2bf(fmaf(bflo(wq0), sa[0], bfhi(wq0)));
      Mout[off0 + NMAT] = f2bf(fmaf(bflo(wq1), sa[1], bfhi(wq1)));
      Mout[off0 + 2 * NMAT] = f2bf(fmaf(bflo(wq2), sa[2], bfhi(wq2)));
      Mout[off0 + 3 * NMAT] = f2bf(fmaf(bflo(wq3), sa[3], bfhi(wq3)));
    }
  }
}

extern "C" void kernel_launch(void* const* d_in, const int* in_sizes, int n_in,
                              void* d_out, int out_size, void* d_ws,
                              size_t ws_size, hipStream_t stream) {
  const float* A1 = (const float*)d_in[0];
  const float* A2 = (const float*)d_in[1];
  const float* N1 = (const float*)d_in[2];
  const float* N2 = (const float*)d_in[3];
  const float* H = (const float*)d_in[4];
  float* s_out = (float*)d_out;

  char* p = (char*)d_ws;
  auto take = [&](size_t bytes) {
    char* r = p;
    p += (bytes + 255) & ~(size_t)255;
    return r;
  };
  unsigned short* idx1 = (unsigned short*)take((size_t)NMAT * CAP * 2);
  unsigned short* idx2 = (unsigned short*)take((size_t)NMAT * CAP * 2);
  unsigned short* idx2T4 = (unsigned short*)take((size_t)CAP * NMAT * 2);
  int* cnt1 = (int*)take((size_t)NMAT * 4);
  int* cnt2 = (int*)take((size_t)NMAT * 4);
  float* N1n = (float*)take((size_t)NMAT * KATTR * 4);
  float* N2n = (float*)take((size_t)NMAT * KATTR * 4);
  float* C1 = (float*)take((size_t)NMAT * KATTR * 4);
  float* C2 = (float*)take((size_t)NMAT * KATTR * 4);
  float* Ht = (float*)take((size_t)NMAT * NMAT * 4);
  unsigned* QM = (unsigned*)take((size_t)NMAT * NMAT * 4);
  unsigned* QL = (unsigned*)take((size_t)NMAT * NMAT * 4);
  unsigned short* Mb0 = (unsigned short*)take((size_t)(NMAT + 1) * NMAT * 2);
  unsigned short* Mb1 = (unsigned short*)take((size_t)(NMAT + 1) * NMAT * 2);
  if ((size_t)(p - (char*)d_ws) > ws_size) return;

  k_build<<<NMAT, 256, 0, stream>>>(A1, idx1, (unsigned short*)nullptr, cnt1);
  k_build<<<NMAT, 256, 0, stream>>>(A2, idx2, idx2T4, cnt2);
  k_norm<<<NMAT / 4, 256, 0, stream>>>(N1, N1n);
  k_norm<<<NMAT / 4, 256, 0, stream>>>(N2, N2n);
  k_gatherN<<<NMAT, 64, 0, stream>>>(idx1, cnt1, N1n, C1);
  k_gatherN<<<NMAT, 64, 0, stream>>>(idx2, cnt2, N2n, C2);
  k_transpose<<<dim3(32, 32), 256, 0, stream>>>(H, Ht);
  k_q<<<dim3(32, 32), 256, 0, stream>>>(N1n, C1, N2n, C2, Ht, QM, QL, Mb0);
  k_zrow<<<1, 1024, 0, stream>>>(Mb0, Mb1);
  for (int it = 0; it < NITER; ++it) {
    const unsigned short* Min = (it & 1) ? Mb1 : Mb0;
    unsigned short* Mout = (it & 1) ? Mb0 : Mb1;
    int last = (it == NITER - 1) ? 1 : 0;
    const unsigned* QMx = last ? QL : QM;
    k_iter<<<NMAT / 4, 1024, 0, stream>>>(idx1, cnt1, idx2T4, cnt2, Min, QMx,
                                          Mout, s_out, last);
  }
}